// Round 4
// baseline (838.579 us; speedup 1.0000x reference)
//
#include <hip/hip_runtime.h>

#define NUM_DOCS 1000000
#define VOCAB 30522
#define NNZ 64000000LL
#define Q_NNZ 32
#define TOP_K 100
#define BM_WORDS 954     // ceil(30522/32)
#define NSLOT 64         // sharded candidate counters (avoid single-address atomic serialization)
#define CAND_SEG 4096    // per-slot candidate capacity (~1015 expected, 4 sigma margin)
#define FCAP 2048        // filtered-candidate LDS capacity (~200 expected)

typedef int   v4i __attribute__((ext_vector_type(4)));

// ---- workspace layout (units of 4 bytes) ----
#define OFF_HIST    0                          // 65536 uints
#define OFF_PART    65536                      // 256 uints (per-block hist partials)
#define OFF_DONE    (OFF_PART + 256)           // 1 uint
#define OFF_THRESH  (OFF_DONE + 1)             // 1 uint
#define OFF_CNT     (OFF_THRESH + 15)          // NSLOT uints
#define OFF_CANDS   (OFF_CNT + NSLOT)          // NSLOT*CAND_SEG floats
#define OFF_CANDI   (OFF_CANDS + NSLOT*CAND_SEG) // NSLOT*CAND_SEG ints
#define ZERO_WORDS  OFF_CANDS                  // hist + part + done + thresh + counters

// Per-doc scores, fused histogram + positive-candidate compaction.
// Streams ONLY doc_indices (256 MB, nontemporal int4, fully coalesced); dv loaded
// scalar on bitmap hit (~0.1% of nnz). Query kept as LDS (bitmap + 32 (qi,qv) pairs);
// hit value = sum of qv where qi matches (coalesces duplicate q indices).
// 16 lanes/doc -> shfl reduce; writer lane emits hist + candidate only if s>0 (~6.5% of docs).
// GRID MUST BE EXACTLY NNZ/4/256 = 62500 blocks.
__global__ __launch_bounds__(256) void score_kernel(
        const float* __restrict__ dv, const int* __restrict__ di,
        const int* __restrict__ qi, const float* __restrict__ qv,
        unsigned* __restrict__ hist, unsigned* __restrict__ cnt,
        float* __restrict__ cs, int* __restrict__ ci) {
    __shared__ unsigned bm[BM_WORDS];
    __shared__ int   qiS[Q_NNZ];
    __shared__ float qvS[Q_NNZ];
    for (int i = threadIdx.x; i < BM_WORDS; i += 256) bm[i] = 0u;
    __syncthreads();
    if (threadIdx.x < Q_NNZ) {
        int v = qi[threadIdx.x];
        qiS[threadIdx.x] = v;
        qvS[threadIdx.x] = qv[threadIdx.x];
        atomicOr(&bm[v >> 5], 1u << (v & 31));
    }
    __syncthreads();

    int t = blockIdx.x * 256 + threadIdx.x;        // 0 .. 16M
    long long base = (long long)t * 4;
    v4i x = __builtin_nontemporal_load((const v4i*)(di + base));
    float s = 0.f;
#define ELEM(xx, off)                                                   \
    if ((bm[(xx) >> 5] >> ((xx) & 31)) & 1u) {                          \
        float qs = 0.f;                                                 \
        for (int j = 0; j < Q_NNZ; ++j)                                 \
            if (qiS[j] == (xx)) qs += qvS[j];                           \
        s += dv[base + (off)] * qs;                                     \
    }
    ELEM(x.x, 0) ELEM(x.y, 1) ELEM(x.z, 2) ELEM(x.w, 3)
#undef ELEM
    s += __shfl_xor(s, 1);
    s += __shfl_xor(s, 2);
    s += __shfl_xor(s, 4);
    s += __shfl_xor(s, 8);
    if ((threadIdx.x & 15) == 0 && s > 0.f) {
        int doc = t >> 4;
        atomicAdd(&hist[__float_as_uint(s) >> 16], 1u);
        int slot = blockIdx.x & (NSLOT - 1);
        unsigned p = atomicAdd(&cnt[slot], 1u);
        if (p < CAND_SEG) {
            cs[slot * CAND_SEG + p] = s;
            ci[slot * CAND_SEG + p] = doc;
        }
    }
}

// Threshold: 256 blocks each reduce one 256-bin chunk; last block (atomic done
// counter) finds the superbin then scans its 256 bins from LDS. Device-scope
// atomics keep part[] coherent across XCDs.
__global__ __launch_bounds__(256) void thresh_kernel(
        const unsigned* __restrict__ hist, unsigned* __restrict__ part,
        unsigned* __restrict__ done, unsigned* __restrict__ thresh) {
    int b = blockIdx.x, t = threadIdx.x;
    unsigned s = hist[b * 256 + t];
    for (int off = 1; off < 64; off <<= 1) s += __shfl_xor(s, off);
    __shared__ unsigned wsum[4];
    if ((t & 63) == 0) wsum[t >> 6] = s;
    __syncthreads();
    if (t == 0) {
        atomicAdd(&part[b], wsum[0] + wsum[1] + wsum[2] + wsum[3]);
        __threadfence();
    }
    __shared__ int lastflag;
    if (t == 0) lastflag = (atomicAdd(done, 1u) == 255u) ? 1 : 0;
    __syncthreads();
    if (!lastflag) return;

    __shared__ unsigned parts[256];
    parts[t] = atomicAdd(&part[t], 0u);   // coherent read
    __syncthreads();
    __shared__ int sc;
    __shared__ unsigned scum;
    if (t == 0) {
        unsigned cum = 0;
        int c = 255;
        for (; c >= 0; --c) {
            if (cum + parts[c] >= TOP_K) break;
            cum += parts[c];
        }
        sc = c; scum = cum;
    }
    __syncthreads();
    int c = sc;
    __shared__ unsigned bins[256];
    if (c >= 0) bins[t] = hist[c * 256 + t];
    __syncthreads();
    if (t == 0) {
        unsigned bin = 1;   // fallback: <TOP_K positive scores (can't happen here)
        if (c >= 0) {
            unsigned cum = scum;
            int b2 = 255;
            for (; b2 >= 0; --b2) {
                cum += bins[b2];
                if (cum >= TOP_K) break;
            }
            if (b2 < 0) b2 = 0;
            bin = (unsigned)(c * 256 + b2);
        }
        thresh[0] = bin << 16;
    }
}

// One block: filter 64 candidate segments against threshold into LDS (~100-300
// survive), then wave 0 iteratively selects top-100 (score desc, doc asc --
// matches jax shard-split + merge tie-break order).
__global__ __launch_bounds__(1024) void select_kernel(
        const unsigned* __restrict__ cnt, const unsigned* __restrict__ thresh,
        const float* __restrict__ cs, const int* __restrict__ ci,
        float* __restrict__ out) {
    __shared__ float fs[FCAP];
    __shared__ int   fi[FCAP];
    __shared__ int   m;
    __shared__ int   ns[NSLOT];
    int t = threadIdx.x;
    if (t == 0) m = 0;
    if (t < NSLOT) ns[t] = (int)min(cnt[t], (unsigned)CAND_SEG);
    __syncthreads();
    unsigned th = thresh[0];
    for (int slot = 0; slot < NSLOT; ++slot) {
        int n = ns[slot];
        for (int i = t; i < n; i += 1024) {
            float s = cs[slot * CAND_SEG + i];
            if (__float_as_uint(s) >= th) {
                int p = atomicAdd(&m, 1);
                if (p < FCAP) { fs[p] = s; fi[p] = ci[slot * CAND_SEG + i]; }
            }
        }
    }
    __syncthreads();
    if (t >= 64) return;
    int n = min(m, FCAP);
    for (int k = 0; k < TOP_K; ++k) {
        float best = -1.f; int bestd = 0x7fffffff; int bestp = -1;
        for (int i = t; i < n; i += 64) {
            float s = fs[i];
            int   d = fi[i];
            if (s > best || (s == best && d < bestd)) { best = s; bestd = d; bestp = i; }
        }
        for (int off = 1; off < 64; off <<= 1) {
            float os = __shfl_xor(best,  off);
            int   od = __shfl_xor(bestd, off);
            int   op = __shfl_xor(bestp, off);
            if (os > best || (os == best && od < bestd)) { best = os; bestd = od; bestp = op; }
        }
        if (t == 0) {
            out[k]         = (bestp >= 0) ? best : 0.f;
            out[TOP_K + k] = (float)((bestp >= 0) ? bestd : 0);
            if (bestp >= 0) fs[bestp] = -1.f;
        }
        __syncthreads();
    }
}

extern "C" void kernel_launch(void* const* d_in, const int* in_sizes, int n_in,
                              void* d_out, int out_size, void* d_ws, size_t ws_size,
                              hipStream_t stream) {
    const float* doc_values  = (const float*)d_in[0];
    const float* q_values    = (const float*)d_in[1];
    const int*   doc_indices = (const int*)d_in[2];
    // d_in[3] = row_ids: implicit (row = nnz/64), never read
    const int*   q_indices   = (const int*)d_in[4];
    float* out = (float*)d_out;

    unsigned* hist   = (unsigned*)d_ws + OFF_HIST;
    unsigned* part   = (unsigned*)d_ws + OFF_PART;
    unsigned* done   = (unsigned*)d_ws + OFF_DONE;
    unsigned* thresh = (unsigned*)d_ws + OFF_THRESH;
    unsigned* cnt    = (unsigned*)d_ws + OFF_CNT;
    float*    cs     = (float*)d_ws + OFF_CANDS;
    int*      ci     = (int*)d_ws + OFF_CANDI;

    // zero hist + partials + counters (ws re-poisoned to 0xAA each launch)
    hipMemsetAsync(d_ws, 0, (size_t)ZERO_WORDS * 4, stream);

    // NNZ/4 threads = 16M -> EXACTLY 62500 blocks of 256
    score_kernel<<<62500, 256, 0, stream>>>(doc_values, doc_indices, q_indices, q_values,
                                            hist, cnt, cs, ci);
    thresh_kernel<<<256, 256, 0, stream>>>(hist, part, done, thresh);
    select_kernel<<<1, 1024, 0, stream>>>(cnt, thresh, cs, ci, out);
}